// Round 2
// baseline (565.245 us; speedup 1.0000x reference)
//
#include <hip/hip_runtime.h>
#include <stdint.h>

// Problem constants: B=2, S=2048, D=1024, H=16, HD=64
#define BB 2
#define SS 2048
#define DD 1024
#define HH 16
#define HD 64
#define BH 32    // B*H
#define BS 4096  // B*S

typedef short bf16x8 __attribute__((ext_vector_type(8)));
typedef float f32x4 __attribute__((ext_vector_type(4)));

static __device__ __forceinline__ unsigned short f2bf(float f) {
    union { float f; unsigned int u; } x;
    x.f = f;
    unsigned int u = x.u;
    unsigned int r = u + 0x7FFFu + ((u >> 16) & 1u);  // round-to-nearest-even
    return (unsigned short)(r >> 16);
}

// ---------------------------------------------------------------- prep kernels

__global__ __launch_bounds__(256) void convert_x_bf16(
    const float* __restrict__ in, unsigned short* __restrict__ out) {
    int i = (blockIdx.x * 256 + threadIdx.x) * 4;
    float4 v = *(const float4*)(in + i);
    ushort4 o;
    o.x = f2bf(v.x); o.y = f2bf(v.y); o.z = f2bf(v.z); o.w = f2bf(v.w);
    *(ushort4*)(out + i) = o;
}

// WT[n][k] = bf16(W[k][n]);  W is [K][N] row-major
__global__ __launch_bounds__(256) void transpose_to_bf16(
    const float* __restrict__ W, unsigned short* __restrict__ WT, int K, int N) {
    __shared__ float tile[32][33];
    int k0 = blockIdx.y * 32, n0 = blockIdx.x * 32;
    int tx = threadIdx.x, ty = threadIdx.y;  // 32 x 8
#pragma unroll
    for (int i = 0; i < 4; i++)
        tile[ty + i * 8][tx] = W[(size_t)(k0 + ty + i * 8) * N + n0 + tx];
    __syncthreads();
#pragma unroll
    for (int i = 0; i < 4; i++)
        WT[(size_t)(n0 + ty + i * 8) * K + k0 + tx] = f2bf(tile[tx][ty + i * 8]);
}

// pack mask floats (0.0 / 1.0) into bits; bit j of word w = mask[w*32+j] != 0
__global__ __launch_bounds__(256) void pack_mask(
    const float* __restrict__ mask, unsigned int* __restrict__ mbits) {
    size_t i = (size_t)blockIdx.x * 256 + threadIdx.x;
    float v = mask[i];
    unsigned long long bal = __ballot(v != 0.0f);
    int lane = threadIdx.x & 63;
    if (lane == 0)       mbits[i >> 5] = (unsigned int)bal;
    else if (lane == 32) mbits[i >> 5] = (unsigned int)(bal >> 32);
}

// ---------------------------------------------------------------- QKV GEMM
// C[4096,3072] = xb[4096,1024] @ Wqkv + bqkv, epilogue scatters into
// q_ws/k_ws : [BH][S][HD] bf16,  vB : [BH][S/8][HD][8] bf16 (B-fragment blocked)
__global__ __launch_bounds__(256) void qkv_gemm(
    const unsigned short* __restrict__ xb,     // [4096][1024]
    const unsigned short* __restrict__ WqkvT,  // [3072][1024]
    const float* __restrict__ bqkv,            // [3072]
    unsigned short* __restrict__ q_ws,
    unsigned short* __restrict__ k_ws,
    unsigned short* __restrict__ vB) {
    int tid = threadIdx.x;
    int w = tid >> 6, lane = tid & 63, quad = lane >> 4, l15 = lane & 15;
    int gx = blockIdx.x;
    int tile_n = (gx % 48) * 64;
    int tile_m = (gx / 48) * 64;

    const unsigned short* arow = xb + (size_t)(tile_m + w * 16 + l15) * 1024 + quad * 8;
    const unsigned short* brow = WqkvT + (size_t)(tile_n + l15) * 1024 + quad * 8;

    f32x4 acc[4] = {};
    for (int k0 = 0; k0 < 1024; k0 += 32) {
        bf16x8 a = *(const bf16x8*)(arow + k0);
#pragma unroll
        for (int nt = 0; nt < 4; nt++) {
            bf16x8 b = *(const bf16x8*)(brow + (size_t)nt * 16 * 1024 + k0);
            acc[nt] = __builtin_amdgcn_mfma_f32_16x16x32_bf16(a, b, acc[nt], 0, 0, 0);
        }
    }

    // epilogue: C/D layout row = quad*4+r, col = nt*16+l15
    int t = tile_n >> 10;                 // 0:Q 1:K 2:V  (uniform per block)
    int hh = (tile_n >> 6) & 15;          // head (uniform per block)
    int Rbase = tile_m + w * 16 + quad * 4;
    int b = Rbase >> 11;
    int sbase = Rbase & 2047;
    int bh = b * 16 + hh;

    if (t == 2) {
        int kblk = sbase >> 3;
        int off = sbase & 7;  // 0 or 4
#pragma unroll
        for (int nt = 0; nt < 4; nt++) {
            int hd = nt * 16 + l15;
            float bias = bqkv[tile_n + nt * 16 + l15];
            ushort4 pk;
            pk.x = f2bf(acc[nt][0] + bias);
            pk.y = f2bf(acc[nt][1] + bias);
            pk.z = f2bf(acc[nt][2] + bias);
            pk.w = f2bf(acc[nt][3] + bias);
            unsigned short* dst = vB + ((size_t)(bh * 256 + kblk)) * 512 + hd * 8 + off;
            *(ushort4*)dst = pk;
        }
    } else {
        unsigned short* dst_ws = (t == 0) ? q_ws : k_ws;
#pragma unroll
        for (int nt = 0; nt < 4; nt++) {
            int hd = nt * 16 + l15;
            float bias = bqkv[tile_n + nt * 16 + l15];
#pragma unroll
            for (int r = 0; r < 4; r++) {
                int s = sbase + r;
                dst_ws[((size_t)(bh * 2048 + s)) * 64 + hd] = f2bf(acc[nt][r] + bias);
            }
        }
    }
}

// ---------------------------------------------------------------- attention
// flash-style online softmax; 1 block = (b,h, 64-q-row tile); 4 waves x 16 rows
__global__ __launch_bounds__(256) void attn(
    const unsigned short* __restrict__ q_ws,  // [BH][S][HD]
    const unsigned short* __restrict__ k_ws,  // [BH][S][HD]
    const unsigned short* __restrict__ vB,    // [BH][S/8][HD][8]
    const unsigned int* __restrict__ mbits,   // [B*S][S/32]
    unsigned short* __restrict__ o_ws) {      // [H][B][S][HD] flat (faithful reshape)
    __shared__ unsigned short p_lds[4][16 * 68];  // per-wave 16x64 P tile, stride 68

    int tid = threadIdx.x;
    int w = tid >> 6, lane = tid & 63, quad = lane >> 4, l15 = lane & 15;
    int bx = blockIdx.x;
    int bh = bx >> 5, qt = bx & 31;
    int b = bh >> 4, h = bh & 15;

    // Q A-fragment rows (m = l15), k = quad*8+j (+32*ks)
    int qrowA = qt * 64 + w * 16 + l15;
    const unsigned short* qptr = q_ws + ((size_t)(bh * 2048 + qrowA)) * 64 + quad * 8;
    bf16x8 qf0 = *(const bf16x8*)(qptr);
    bf16x8 qf1 = *(const bf16x8*)(qptr + 32);

    int qrowC = qt * 64 + w * 16 + quad * 4;  // + r  (C-layout rows)
    const unsigned int* mb = mbits + ((size_t)(b * 2048 + qrowC)) * 64;

    float m_i[4], l_i[4];
    f32x4 oacc[4] = {};
#pragma unroll
    for (int r = 0; r < 4; r++) { m_i[r] = -1e30f; l_i[r] = 0.0f; }

    const unsigned short* kbase = k_ws + (size_t)bh * 2048 * 64;
    const unsigned short* vbase = vB + (size_t)bh * 256 * 512;
    unsigned short* p_my = &p_lds[w][0];

    for (int kt = 0; kt < 32; kt++) {
        // ---- S = Q K^T  (B-frag: n = key = l15, k = hd = quad*8+j)
        f32x4 sacc[4];
#pragma unroll
        for (int nt = 0; nt < 4; nt++) {
            const unsigned short* kp =
                kbase + (size_t)(kt * 64 + nt * 16 + l15) * 64 + quad * 8;
            bf16x8 kf0 = *(const bf16x8*)kp;
            bf16x8 kf1 = *(const bf16x8*)(kp + 32);
            f32x4 z = {};
            z = __builtin_amdgcn_mfma_f32_16x16x32_bf16(qf0, kf0, z, 0, 0, 0);
            z = __builtin_amdgcn_mfma_f32_16x16x32_bf16(qf1, kf1, z, 0, 0, 0);
            sacc[nt] = z;
        }
        // ---- scale + mask (bitmask; word = 32 keys)
        float sc[4][4];
#pragma unroll
        for (int r = 0; r < 4; r++) {
            unsigned int w0 = mb[r * 64 + kt * 2];
            unsigned int w1 = mb[r * 64 + kt * 2 + 1];
#pragma unroll
            for (int nt = 0; nt < 4; nt++) {
                int kk = nt * 16 + l15;
                unsigned int wd = (kk >= 32) ? w1 : w0;
                float msub = ((wd >> (kk & 31)) & 1u) ? -1e9f : 0.0f;
                sc[nt][r] = sacc[nt][r] * 0.125f + msub;
            }
        }
        // ---- online softmax (row lives in 16 lanes of a quad, 4 rows as regs)
        float alpha[4];
#pragma unroll
        for (int r = 0; r < 4; r++) {
            float v = fmaxf(fmaxf(sc[0][r], sc[1][r]), fmaxf(sc[2][r], sc[3][r]));
            v = fmaxf(v, __shfl_xor(v, 1, 16));
            v = fmaxf(v, __shfl_xor(v, 2, 16));
            v = fmaxf(v, __shfl_xor(v, 4, 16));
            v = fmaxf(v, __shfl_xor(v, 8, 16));
            float mn = fmaxf(m_i[r], v);
            alpha[r] = __expf(m_i[r] - mn);
            m_i[r] = mn;
            float s0 = 0.0f;
#pragma unroll
            for (int nt = 0; nt < 4; nt++) {
                float p = __expf(sc[nt][r] - mn);
                sc[nt][r] = p;
                s0 += p;
            }
            s0 += __shfl_xor(s0, 1, 16);
            s0 += __shfl_xor(s0, 2, 16);
            s0 += __shfl_xor(s0, 4, 16);
            s0 += __shfl_xor(s0, 8, 16);
            l_i[r] = l_i[r] * alpha[r] + s0;
        }
#pragma unroll
        for (int nb = 0; nb < 4; nb++)
#pragma unroll
            for (int r = 0; r < 4; r++) oacc[nb][r] *= alpha[r];

        // ---- P: C-layout -> LDS -> A-layout (per-wave region, no barrier needed)
#pragma unroll
        for (int nt = 0; nt < 4; nt++)
#pragma unroll
            for (int r = 0; r < 4; r++)
                p_my[(quad * 4 + r) * 68 + nt * 16 + l15] = f2bf(sc[nt][r]);

        // ---- O += P V   (A-frag of P from LDS; V B-frag contiguous via vB layout)
        // NOTE: read via __builtin_memcpy (char-typed) so the compiler cannot
        // reorder these ds_reads above the ushort ds_writes (TBAA hazard that
        // produced NaN in round 0).
#pragma unroll
        for (int ks2 = 0; ks2 < 2; ks2++) {
            bf16x8 pa;
            const unsigned short* pp = p_my + l15 * 68 + ks2 * 32 + quad * 8;
            __builtin_memcpy(&pa, pp, 16);
#pragma unroll
            for (int nb = 0; nb < 4; nb++) {
                const unsigned short* vp =
                    vbase + (size_t)(kt * 8 + ks2 * 4 + quad) * 512 + (nb * 16 + l15) * 8;
                bf16x8 vf = *(const bf16x8*)vp;
                oacc[nb] = __builtin_amdgcn_mfma_f32_16x16x32_bf16(pa, vf, oacc[nb], 0, 0, 0);
            }
        }
    }

    // ---- normalize + store in faithful [H][B][S][HD] flat layout
#pragma unroll
    for (int nb = 0; nb < 4; nb++) {
        int hd = nb * 16 + l15;
#pragma unroll
        for (int r = 0; r < 4; r++) {
            float o = oacc[nb][r] / l_i[r];
            int q = qrowC + r;
            o_ws[((size_t)((h * 2 + b) * 2048 + q)) * 64 + hd] = f2bf(o);
        }
    }
}

// ---------------------------------------------------------------- output GEMM
// out[4096,1024] = o_ws[4096,1024] @ Wo + bo   (f32 out)
__global__ __launch_bounds__(256) void out_gemm(
    const unsigned short* __restrict__ Amat,  // o_ws flat [4096][1024]
    const unsigned short* __restrict__ WoT,   // [1024][1024]
    const float* __restrict__ bo,
    float* __restrict__ out) {
    int tid = threadIdx.x;
    int w = tid >> 6, lane = tid & 63, quad = lane >> 4, l15 = lane & 15;
    int gx = blockIdx.x;
    int tile_n = (gx % 16) * 64;
    int tile_m = (gx / 16) * 64;

    const unsigned short* arow = Amat + (size_t)(tile_m + w * 16 + l15) * 1024 + quad * 8;
    const unsigned short* brow = WoT + (size_t)(tile_n + l15) * 1024 + quad * 8;

    f32x4 acc[4] = {};
    for (int k0 = 0; k0 < 1024; k0 += 32) {
        bf16x8 a = *(const bf16x8*)(arow + k0);
#pragma unroll
        for (int nt = 0; nt < 4; nt++) {
            bf16x8 b = *(const bf16x8*)(brow + (size_t)nt * 16 * 1024 + k0);
            acc[nt] = __builtin_amdgcn_mfma_f32_16x16x32_bf16(a, b, acc[nt], 0, 0, 0);
        }
    }
    int Rbase = tile_m + w * 16 + quad * 4;
#pragma unroll
    for (int nt = 0; nt < 4; nt++) {
        int col = tile_n + nt * 16 + l15;
        float bias = bo[col];
#pragma unroll
        for (int r = 0; r < 4; r++)
            out[(size_t)(Rbase + r) * 1024 + col] = acc[nt][r] + bias;
    }
}

// ---------------------------------------------------------------- launch

extern "C" void kernel_launch(void* const* d_in, const int* in_sizes, int n_in,
                              void* d_out, int out_size, void* d_ws, size_t ws_size,
                              hipStream_t stream) {
    const float* x    = (const float*)d_in[0];
    const float* mask = (const float*)d_in[1];
    const float* Wqkv = (const float*)d_in[2];
    const float* bqkv = (const float*)d_in[3];
    const float* Wo   = (const float*)d_in[4];
    const float* bo   = (const float*)d_in[5];
    float* out = (float*)d_out;

    char* ws = (char*)d_ws;
    unsigned short* xb    = (unsigned short*)(ws);                       // 8 MB
    unsigned short* WqkvT = (unsigned short*)(ws + ((size_t)8 << 20));   // 6 MB
    unsigned short* WoT   = (unsigned short*)(ws + ((size_t)14 << 20));  // 2 MB
    unsigned short* q_ws  = (unsigned short*)(ws + ((size_t)16 << 20));  // 8 MB
    unsigned short* k_ws  = (unsigned short*)(ws + ((size_t)24 << 20));  // 8 MB
    unsigned short* vB    = (unsigned short*)(ws + ((size_t)32 << 20));  // 8 MB
    unsigned short* o_ws  = (unsigned short*)(ws + ((size_t)40 << 20));  // 8 MB
    unsigned int*   mbits = (unsigned int*)(ws + ((size_t)48 << 20));    // 1 MB

    convert_x_bf16<<<4096, 256, 0, stream>>>(x, xb);  // 4M elems / 4 / 256
    dim3 tb(32, 8);
    transpose_to_bf16<<<dim3(3072 / 32, 1024 / 32), tb, 0, stream>>>(Wqkv, WqkvT, 1024, 3072);
    transpose_to_bf16<<<dim3(1024 / 32, 1024 / 32), tb, 0, stream>>>(Wo, WoT, 1024, 1024);
    pack_mask<<<(BB * SS * SS) / 256, 256, 0, stream>>>(mask, mbits);
    qkv_gemm<<<64 * 48, 256, 0, stream>>>(xb, WqkvT, bqkv, q_ws, k_ws, vB);
    attn<<<1024, 256, 0, stream>>>(q_ws, k_ws, vB, mbits, o_ws);
    out_gemm<<<64 * 16, 256, 0, stream>>>(o_ws, WoT, bo, out);
}

// Round 3
// 349.970 us; speedup vs baseline: 1.6151x; 1.6151x over previous
//
#include <hip/hip_runtime.h>
#include <stdint.h>

// Problem constants: B=2, S=2048, D=1024, H=16, HD=64
#define BB 2
#define SS 2048
#define DD 1024
#define HH 16
#define HD 64
#define BH 32    // B*H
#define BS 4096  // B*S

typedef short bf16x8 __attribute__((ext_vector_type(8)));
typedef float f32x4 __attribute__((ext_vector_type(4)));

static __device__ __forceinline__ unsigned short f2bf(float f) {
    union { float f; unsigned int u; } x;
    x.f = f;
    unsigned int u = x.u;
    unsigned int r = u + 0x7FFFu + ((u >> 16) & 1u);  // round-to-nearest-even
    return (unsigned short)(r >> 16);
}

// async global->LDS, 16B per lane; LDS dst is wave-uniform base + lane*16
static __device__ __forceinline__ void gld16(unsigned short* lds, const unsigned short* g) {
    __builtin_amdgcn_global_load_lds(
        (const __attribute__((address_space(1))) unsigned int*)g,
        (__attribute__((address_space(3))) unsigned int*)lds,
        16, 0, 0);
}

// ---------------------------------------------------------------- prep kernels

__global__ __launch_bounds__(256) void convert_x_bf16(
    const float* __restrict__ in, unsigned short* __restrict__ out) {
    int i = (blockIdx.x * 256 + threadIdx.x) * 4;
    float4 v = *(const float4*)(in + i);
    ushort4 o;
    o.x = f2bf(v.x); o.y = f2bf(v.y); o.z = f2bf(v.z); o.w = f2bf(v.w);
    *(ushort4*)(out + i) = o;
}

// WT[n][k] = bf16(W[k][n]);  W is [K][N] row-major
__global__ __launch_bounds__(256) void transpose_to_bf16(
    const float* __restrict__ W, unsigned short* __restrict__ WT, int K, int N) {
    __shared__ float tile[32][33];
    int k0 = blockIdx.y * 32, n0 = blockIdx.x * 32;
    int tx = threadIdx.x, ty = threadIdx.y;  // 32 x 8
#pragma unroll
    for (int i = 0; i < 4; i++)
        tile[ty + i * 8][tx] = W[(size_t)(k0 + ty + i * 8) * N + n0 + tx];
    __syncthreads();
#pragma unroll
    for (int i = 0; i < 4; i++)
        WT[(size_t)(n0 + ty + i * 8) * K + k0 + tx] = f2bf(tile[tx][ty + i * 8]);
}

// pack mask floats (0.0 / 1.0) into bits; bit j of word w = mask[w*32+j] != 0
__global__ __launch_bounds__(256) void pack_mask(
    const float* __restrict__ mask, unsigned int* __restrict__ mbits) {
    size_t i = (size_t)blockIdx.x * 256 + threadIdx.x;
    float v = mask[i];
    unsigned long long bal = __ballot(v != 0.0f);
    int lane = threadIdx.x & 63;
    if (lane == 0)       mbits[i >> 5] = (unsigned int)bal;
    else if (lane == 32) mbits[i >> 5] = (unsigned int)(bal >> 32);
}

// ---------------------------------------------------------------- 128x128 GEMM mainloop
// A:[M][K] bf16 row-major, Bt:[N][K] bf16 row-major. 256 threads = 4 waves in 2x2,
// each wave a 64x64 tile (4x4 MFMA 16x16x32). LDS-staged via global_load_lds w=16.
// Chunk swizzle: LDS pos p of row r holds global chunk c with p=(c+(r>>1))&3 —
// breaks the stride-64B bank aliasing for the consumer ds_read_b128.
template <int KDIM>
static __device__ __forceinline__ void mm128_loop(
    const unsigned short* __restrict__ A, const unsigned short* __restrict__ Bt,
    int m0, int n0, unsigned short* ldsA, unsigned short* ldsB, f32x4 acc[4][4]) {
    int tid = threadIdx.x;
    int w = tid >> 6, lane = tid & 63, quad = lane >> 4, l15 = lane & 15;

    // producer: thread t -> row r = t>>2 (per 64-row half), LDS pos p = t&3
    int r = tid >> 2, p = tid & 3;
    int c = (p - (r >> 1)) & 3;  // global chunk to fetch so LDS pos p is swizzled
    const unsigned short* gA0 = A + (size_t)(m0 + r) * KDIM + c * 8;
    const unsigned short* gA1 = gA0 + (size_t)64 * KDIM;
    const unsigned short* gB0 = Bt + (size_t)(n0 + r) * KDIM + c * 8;
    const unsigned short* gB1 = gB0 + (size_t)64 * KDIM;
    unsigned short* lA0 = ldsA + w * 512;         // bytes: w*1024
    unsigned short* lA1 = ldsA + 2048 + w * 512;  // rows 64..127
    unsigned short* lB0 = ldsB + w * 512;
    unsigned short* lB1 = ldsB + 2048 + w * 512;

    // consumer fragment offsets (short units): row*32 + pos*8
    int wm = w >> 1, wn = w & 1;
    int posq = ((quad + (l15 >> 1)) & 3) * 8;
    int aoff = (wm * 64 + l15) * 32 + posq;
    int boff = (wn * 64 + l15) * 32 + posq;

    for (int k0 = 0; k0 < KDIM; k0 += 32) {
        __syncthreads();  // previous tile fully consumed
        gld16(lA0, gA0 + k0);
        gld16(lA1, gA1 + k0);
        gld16(lB0, gB0 + k0);
        gld16(lB1, gB1 + k0);
        __syncthreads();  // drains vmcnt(0): staged data visible
        bf16x8 af[4], bfr[4];
#pragma unroll
        for (int i = 0; i < 4; i++) {
            af[i]  = *(const bf16x8*)(ldsA + aoff + i * 512);  // +16 rows
            bfr[i] = *(const bf16x8*)(ldsB + boff + i * 512);
        }
#pragma unroll
        for (int i = 0; i < 4; i++)
#pragma unroll
            for (int j = 0; j < 4; j++)
                acc[i][j] = __builtin_amdgcn_mfma_f32_16x16x32_bf16(af[i], bfr[j], acc[i][j], 0, 0, 0);
    }
}

// ---------------------------------------------------------------- QKV GEMM
// C[4096,3072] = xb @ WqkvT^T + bqkv; epilogue scatters into
// q_ws/k_ws : [BH][S][HD] bf16,  vB : [BH][S/8][HD][8] bf16
__global__ __launch_bounds__(256) void qkv_gemm(
    const unsigned short* __restrict__ xb,     // [4096][1024]
    const unsigned short* __restrict__ WqkvT,  // [3072][1024]
    const float* __restrict__ bqkv,            // [3072]
    unsigned short* __restrict__ q_ws,
    unsigned short* __restrict__ k_ws,
    unsigned short* __restrict__ vB) {
    __shared__ unsigned short ldsA[4096], ldsB[4096];
    int gx = blockIdx.x;
    int m0 = (gx / 24) * 128, n0 = (gx % 24) * 128;

    f32x4 acc[4][4] = {};
    mm128_loop<1024>(xb, WqkvT, m0, n0, ldsA, ldsB, acc);

    int tid = threadIdx.x;
    int w = tid >> 6, lane = tid & 63, quad = lane >> 4, l15 = lane & 15;
    int wm = w >> 1, wn = w & 1;
    int t = n0 >> 10;                  // 0:Q 1:K 2:V (tile never straddles)
    int ncol0 = n0 + wn * 64;          // 64-aligned -> single head per wave
    int hh = (ncol0 >> 6) & 15;
    int Rb = m0 + wm * 64 + quad * 4;  // + i*16 + r

    if (t == 2) {
        int off = (quad & 1) * 4;
#pragma unroll
        for (int j = 0; j < 4; j++) {
            int hd = j * 16 + l15;
            float bias = bqkv[ncol0 + hd];
#pragma unroll
            for (int i = 0; i < 4; i++) {
                int row = Rb + i * 16;
                int b = row >> 11, s = row & 2047;
                int bh = b * 16 + hh;
                ushort4 pk;
                pk.x = f2bf(acc[i][j][0] + bias);
                pk.y = f2bf(acc[i][j][1] + bias);
                pk.z = f2bf(acc[i][j][2] + bias);
                pk.w = f2bf(acc[i][j][3] + bias);
                *(ushort4*)(vB + ((size_t)(bh * 256 + (s >> 3))) * 512 + hd * 8 + off) = pk;
            }
        }
    } else {
        unsigned short* dst = (t == 0) ? q_ws : k_ws;
#pragma unroll
        for (int j = 0; j < 4; j++) {
            int hd = j * 16 + l15;
            float bias = bqkv[ncol0 + hd];
#pragma unroll
            for (int i = 0; i < 4; i++) {
                int row = Rb + i * 16;
                int b = row >> 11, s = row & 2047;
                int bh = b * 16 + hh;
#pragma unroll
                for (int rr = 0; rr < 4; rr++)
                    dst[((size_t)(bh * 2048 + s + rr)) * 64 + hd] = f2bf(acc[i][j][rr] + bias);
            }
        }
    }
}

// ---------------------------------------------------------------- output GEMM
// out[4096,1024] = o_ws @ WoT^T + bo   (f32 out)
__global__ __launch_bounds__(256) void out_gemm(
    const unsigned short* __restrict__ Amat,  // o_ws flat [4096][1024]
    const unsigned short* __restrict__ WoT,   // [1024][1024]
    const float* __restrict__ bo,
    float* __restrict__ out) {
    __shared__ unsigned short ldsA[4096], ldsB[4096];
    int gx = blockIdx.x;
    int m0 = (gx / 8) * 128, n0 = (gx % 8) * 128;

    f32x4 acc[4][4] = {};
    mm128_loop<1024>(Amat, WoT, m0, n0, ldsA, ldsB, acc);

    int tid = threadIdx.x;
    int w = tid >> 6, lane = tid & 63, quad = lane >> 4, l15 = lane & 15;
    int wm = w >> 1, wn = w & 1;
    int ncol0 = n0 + wn * 64;
    int Rb = m0 + wm * 64 + quad * 4;
#pragma unroll
    for (int j = 0; j < 4; j++) {
        int col = ncol0 + j * 16 + l15;
        float bias = bo[col];
#pragma unroll
        for (int i = 0; i < 4; i++) {
            int row = Rb + i * 16;
#pragma unroll
            for (int rr = 0; rr < 4; rr++)
                out[(size_t)(row + rr) * 1024 + col] = acc[i][j][rr] + bias;
        }
    }
}

// ---------------------------------------------------------------- attention
// flash-style online softmax; 1 block = (b,h, 64-q-row tile); 4 waves x 16 rows
__global__ __launch_bounds__(256) void attn(
    const unsigned short* __restrict__ q_ws,  // [BH][S][HD]
    const unsigned short* __restrict__ k_ws,  // [BH][S][HD]
    const unsigned short* __restrict__ vB,    // [BH][S/8][HD][8]
    const unsigned int* __restrict__ mbits,   // [B*S][S/32]
    unsigned short* __restrict__ o_ws) {      // [H][B][S][HD] flat (faithful reshape)
    __shared__ unsigned short p_lds[4][16 * 68];  // per-wave 16x64 P tile, stride 68

    int tid = threadIdx.x;
    int w = tid >> 6, lane = tid & 63, quad = lane >> 4, l15 = lane & 15;
    int bx = blockIdx.x;
    int bh = bx >> 5, qt = bx & 31;
    int b = bh >> 4, h = bh & 15;

    // Q A-fragment rows (m = l15), k = quad*8+j (+32*ks)
    int qrowA = qt * 64 + w * 16 + l15;
    const unsigned short* qptr = q_ws + ((size_t)(bh * 2048 + qrowA)) * 64 + quad * 8;
    bf16x8 qf0 = *(const bf16x8*)(qptr);
    bf16x8 qf1 = *(const bf16x8*)(qptr + 32);

    int qrowC = qt * 64 + w * 16 + quad * 4;  // + r  (C-layout rows)
    const unsigned int* mb = mbits + ((size_t)(b * 2048 + qrowC)) * 64;

    float m_i[4], l_i[4];
    f32x4 oacc[4] = {};
#pragma unroll
    for (int r = 0; r < 4; r++) { m_i[r] = -1e30f; l_i[r] = 0.0f; }

    const unsigned short* kbase = k_ws + (size_t)bh * 2048 * 64;
    const unsigned short* vbase = vB + (size_t)bh * 256 * 512;
    unsigned short* p_my = &p_lds[w][0];

    for (int kt = 0; kt < 32; kt++) {
        // ---- S = Q K^T  (B-frag: n = key = l15, k = hd = quad*8+j)
        f32x4 sacc[4];
#pragma unroll
        for (int nt = 0; nt < 4; nt++) {
            const unsigned short* kp =
                kbase + (size_t)(kt * 64 + nt * 16 + l15) * 64 + quad * 8;
            bf16x8 kf0 = *(const bf16x8*)kp;
            bf16x8 kf1 = *(const bf16x8*)(kp + 32);
            f32x4 z = {};
            z = __builtin_amdgcn_mfma_f32_16x16x32_bf16(qf0, kf0, z, 0, 0, 0);
            z = __builtin_amdgcn_mfma_f32_16x16x32_bf16(qf1, kf1, z, 0, 0, 0);
            sacc[nt] = z;
        }
        // ---- scale + mask (bitmask; word = 32 keys)
        float sc[4][4];
#pragma unroll
        for (int r = 0; r < 4; r++) {
            unsigned int w0 = mb[r * 64 + kt * 2];
            unsigned int w1 = mb[r * 64 + kt * 2 + 1];
#pragma unroll
            for (int nt = 0; nt < 4; nt++) {
                int kk = nt * 16 + l15;
                unsigned int wd = (kk >= 32) ? w1 : w0;
                float msub = ((wd >> (kk & 31)) & 1u) ? -1e9f : 0.0f;
                sc[nt][r] = sacc[nt][r] * 0.125f + msub;
            }
        }
        // ---- online softmax (row lives in 16 lanes of a quad, 4 rows as regs)
        float alpha[4];
#pragma unroll
        for (int r = 0; r < 4; r++) {
            float v = fmaxf(fmaxf(sc[0][r], sc[1][r]), fmaxf(sc[2][r], sc[3][r]));
            v = fmaxf(v, __shfl_xor(v, 1, 16));
            v = fmaxf(v, __shfl_xor(v, 2, 16));
            v = fmaxf(v, __shfl_xor(v, 4, 16));
            v = fmaxf(v, __shfl_xor(v, 8, 16));
            float mn = fmaxf(m_i[r], v);
            alpha[r] = __expf(m_i[r] - mn);
            m_i[r] = mn;
            float s0 = 0.0f;
#pragma unroll
            for (int nt = 0; nt < 4; nt++) {
                float p = __expf(sc[nt][r] - mn);
                sc[nt][r] = p;
                s0 += p;
            }
            s0 += __shfl_xor(s0, 1, 16);
            s0 += __shfl_xor(s0, 2, 16);
            s0 += __shfl_xor(s0, 4, 16);
            s0 += __shfl_xor(s0, 8, 16);
            l_i[r] = l_i[r] * alpha[r] + s0;
        }
#pragma unroll
        for (int nb = 0; nb < 4; nb++)
#pragma unroll
            for (int r = 0; r < 4; r++) oacc[nb][r] *= alpha[r];

        // ---- P: C-layout -> LDS -> A-layout (per-wave region, no barrier needed)
#pragma unroll
        for (int nt = 0; nt < 4; nt++)
#pragma unroll
            for (int r = 0; r < 4; r++)
                p_my[(quad * 4 + r) * 68 + nt * 16 + l15] = f2bf(sc[nt][r]);

        // ---- O += P V   (A-frag of P from LDS via memcpy: keeps ds_reads after
        // the ushort ds_writes — TBAA hazard produced NaN in round 0)
#pragma unroll
        for (int ks2 = 0; ks2 < 2; ks2++) {
            bf16x8 pa;
            const unsigned short* pp = p_my + l15 * 68 + ks2 * 32 + quad * 8;
            __builtin_memcpy(&pa, pp, 16);
#pragma unroll
            for (int nb = 0; nb < 4; nb++) {
                const unsigned short* vp =
                    vbase + (size_t)(kt * 8 + ks2 * 4 + quad) * 512 + (nb * 16 + l15) * 8;
                bf16x8 vf = *(const bf16x8*)vp;
                oacc[nb] = __builtin_amdgcn_mfma_f32_16x16x32_bf16(pa, vf, oacc[nb], 0, 0, 0);
            }
        }
    }

    // ---- normalize + store in faithful [H][B][S][HD] flat layout
#pragma unroll
    for (int nb = 0; nb < 4; nb++) {
        int hd = nb * 16 + l15;
#pragma unroll
        for (int r = 0; r < 4; r++) {
            float o = oacc[nb][r] / l_i[r];
            int q = qrowC + r;
            o_ws[((size_t)((h * 2 + b) * 2048 + q)) * 64 + hd] = f2bf(o);
        }
    }
}

// ---------------------------------------------------------------- launch

extern "C" void kernel_launch(void* const* d_in, const int* in_sizes, int n_in,
                              void* d_out, int out_size, void* d_ws, size_t ws_size,
                              hipStream_t stream) {
    const float* x    = (const float*)d_in[0];
    const float* mask = (const float*)d_in[1];
    const float* Wqkv = (const float*)d_in[2];
    const float* bqkv = (const float*)d_in[3];
    const float* Wo   = (const float*)d_in[4];
    const float* bo   = (const float*)d_in[5];
    float* out = (float*)d_out;

    char* ws = (char*)d_ws;
    unsigned short* xb    = (unsigned short*)(ws);                       // 8 MB
    unsigned short* WqkvT = (unsigned short*)(ws + ((size_t)8 << 20));   // 6 MB
    unsigned short* WoT   = (unsigned short*)(ws + ((size_t)14 << 20));  // 2 MB
    unsigned short* q_ws  = (unsigned short*)(ws + ((size_t)16 << 20));  // 8 MB
    unsigned short* k_ws  = (unsigned short*)(ws + ((size_t)24 << 20));  // 8 MB
    unsigned short* vB    = (unsigned short*)(ws + ((size_t)32 << 20));  // 8 MB
    unsigned short* o_ws  = (unsigned short*)(ws + ((size_t)40 << 20));  // 8 MB
    unsigned int*   mbits = (unsigned int*)(ws + ((size_t)48 << 20));    // 1 MB

    convert_x_bf16<<<4096, 256, 0, stream>>>(x, xb);
    dim3 tb(32, 8);
    transpose_to_bf16<<<dim3(3072 / 32, 1024 / 32), tb, 0, stream>>>(Wqkv, WqkvT, 1024, 3072);
    transpose_to_bf16<<<dim3(1024 / 32, 1024 / 32), tb, 0, stream>>>(Wo, WoT, 1024, 1024);
    pack_mask<<<(BB * SS * SS) / 256, 256, 0, stream>>>(mask, mbits);
    qkv_gemm<<<32 * 24, 256, 0, stream>>>(xb, WqkvT, bqkv, q_ws, k_ws, vB);
    attn<<<1024, 256, 0, stream>>>(q_ws, k_ws, vB, mbits, o_ws);
    out_gemm<<<32 * 8, 256, 0, stream>>>(o_ws, WoT, bo, out);
}